// Round 1
// baseline (11873.402 us; speedup 1.0000x reference)
//
#include <hip/hip_runtime.h>

#define TT 128
#define BB 64
#define HH 1024
#define LL 4

typedef _Float16 f16;
typedef __attribute__((ext_vector_type(4))) _Float16 f16x4;
typedef __attribute__((ext_vector_type(8))) _Float16 f16x8;
typedef __attribute__((ext_vector_type(4))) float f32x4;

// ---------------- persistent device buffers (re-initialized every launch) ----------------
// Fragment layout for a [64 rows x 1024 k] fp16 tensor:
//   flat = ((rg*32 + ktp)*64 + lane)*8 + e
//   rg = row>>4, ktp = k>>5, lane = ((k>>2)&3)<<4 | (row&15), e = ((k>>4)&1)<<2 | (k&3)
// so that a wave's dwordx4 load at (base + rg*16384 + ktp*512 + lane*8) yields two
// v_mfma_f32_16x16x16f16 A/B fragments (k-halves) with m/n = lane&15, k16 = 4*(lane>>4)+e.
__device__ __align__(16) f16 g_Wpack[LL][256][2][16384]; // [layer][colblk16][mat W/U][frag] = 67 MB
__device__ __align__(16) f16 g_in16[TT][65536];          // inputs, frag layout per t (16.8 MB)
__device__ __align__(16) f16 g_c16[LL][2][65536];        // cell state fp16 (next-layer input), parity-buffered
__device__ __align__(16) f16 g_h16[LL][2][65536];        // hidden state fp16 (U-matmul input), parity-buffered
__device__ __align__(16) float g_c32[LL][BB][HH];        // cell state master f32 (WG-private slices)
__device__ unsigned g_done[LL][TT];                      // completion counters (64 WGs each)

// ---------------- init: zero state + flags ----------------
__global__ void k_init() {
  unsigned tid = blockIdx.x * blockDim.x + threadIdx.x;
  unsigned n = gridDim.x * blockDim.x;
  float* c32 = &g_c32[0][0][0];
  for (unsigned i = tid; i < LL * BB * HH; i += n) c32[i] = 0.f;
  unsigned* p1 = (unsigned*)&g_c16[0][0][0];
  unsigned* p2 = (unsigned*)&g_h16[0][0][0];
  const unsigned nh = LL * 2 * 65536 / 2; // as u32
  for (unsigned i = tid; i < nh; i += n) { p1[i] = 0u; p2[i] = 0u; }
  unsigned* pd = &g_done[0][0];
  for (unsigned i = tid; i < LL * TT; i += n) pd[i] = 0u;
}

// ---------------- pack inputs f32 -> fp16 fragment layout ----------------
__global__ void k_pack_in(const float* __restrict__ inp) {
  int tid = blockIdx.x * blockDim.x + threadIdx.x; // 128*16384 threads
  int t = tid >> 14, q = tid & 16383;
  int row = q >> 8, hu = (q & 255) << 2;
  const float4 x = *(const float4*)(inp + ((size_t)t << 16) + (row << 10) + hu);
  int rg = row >> 4, ktp = hu >> 5;
  int ln = (((hu >> 2) & 3) << 4) | (row & 15);
  int e0 = ((hu >> 4) & 1) << 2;
  f16x4 v = {(f16)x.x, (f16)x.y, (f16)x.z, (f16)x.w};
  *(f16x4*)&g_in16[t][(((rg * 32 + ktp) * 64 + ln) << 3) + e0] = v;
}

// ---------------- pack W,U f32 -> fp16 fragment-linear layout ----------------
// colblk cb = s*4 + gate : orig col = gate*1024 + s*16 + (lane&15)
__global__ void k_pack_w(const float* __restrict__ W, const float* __restrict__ U) {
  int bid = blockIdx.x; // [jj 4][cb 256][mat 2][blk 4]
  int blk = bid & 3, mat = (bid >> 2) & 1, cb = (bid >> 3) & 255, jj = bid >> 11;
  const float* src = (mat ? U : W) + (size_t)jj * HH * 4 * HH;
  int colbase = (cb & 3) * 1024 + (cb >> 2) * 16;
  int o = (blk << 12) | (threadIdx.x << 3);
  int ktp = o >> 9, l = (o >> 3) & 63;
  int col = colbase + (l & 15);
  int kb = ktp * 32 + ((l >> 4) & 3) * 4;
  f16x8 v;
#pragma unroll
  for (int e = 0; e < 8; ++e) {
    int k = kb + ((e >> 2) << 4) + (e & 3);
    v[e] = (f16)src[(size_t)k * 4096 + col];
  }
  *(f16x8*)&g_Wpack[jj][cb][mat][o] = v;
}

// ---------------- main persistent wavefront kernel ----------------
__device__ __forceinline__ float sigf(float x) { return 1.f / (1.f + __expf(-x)); }
__device__ __forceinline__ float tanh_(float x) {
  float q = __expf(-2.f * fabsf(x));
  return copysignf((1.f - q) / (1.f + q), x);
}

#define MFMA16(A_, B_, C_) __builtin_amdgcn_mfma_f32_16x16x16f16(A_, B_, C_, 0, 0, 0)

__global__ __launch_bounds__(512, 2) void k_main(const float* __restrict__ bias,
                                                 float* __restrict__ out) {
  const int j = blockIdx.x >> 6;   // layer
  const int s = blockIdx.x & 63;   // 16-hidden-unit slice
  const int tid = threadIdx.x;
  const int lane = tid & 63;
  const int wave = tid >> 6;
  const int wm = wave >> 1;        // row group (16 rows)
  const int g0 = (wave & 1) * 2;   // first of two gates for this wave
  __shared__ float zl[64][65];     // z tile, padded vs bank conflicts

  const f16* const wpA = &g_Wpack[j][s * 4 + g0][0][0];
  const f16* const wpB = &g_Wpack[j][s * 4 + g0 + 1][0][0];
  const int aoff = wm * 16384 + lane * 8;
  const int boff = lane * 8;

  for (int t = 0; t < TT; ++t) {
    // ---- dependency waits (one spinner, then barrier) ----
    if (tid == 0) {
      if (j > 0)  // cell state from layer below, same t
        while (__hip_atomic_load(&g_done[j - 1][t], __ATOMIC_RELAXED, __HIP_MEMORY_SCOPE_AGENT) < 64u)
          __builtin_amdgcn_s_sleep(1);
      if (t > 0)  // own layer's full h vector from t-1
        while (__hip_atomic_load(&g_done[j][t - 1], __ATOMIC_RELAXED, __HIP_MEMORY_SCOPE_AGENT) < 64u)
          __builtin_amdgcn_s_sleep(1);
      if (j < 3 && t >= 2)  // anti-overwrite: consumers of c16[j][t-2] finished
        while (__hip_atomic_load(&g_done[j + 1][t - 2], __ATOMIC_RELAXED, __HIP_MEMORY_SCOPE_AGENT) < 64u)
          __builtin_amdgcn_s_sleep(1);
      __builtin_amdgcn_fence(__ATOMIC_ACQUIRE, "agent");
    }
    __syncthreads();

    // ---- GEMM: z = x@W + h@U for this wave's 16 rows x 2 gate-columns ----
    f32x4 acc0 = {0.f, 0.f, 0.f, 0.f}, acc1 = {0.f, 0.f, 0.f, 0.f};
    const f16* xb = (j == 0) ? &g_in16[t][0] : &g_c16[j - 1][t & 1][0];
    const f16* hb = &g_h16[j][(t + 1) & 1][0]; // (t-1)&1

#pragma unroll
    for (int mat = 0; mat < 2; ++mat) {
      const f16* A = (mat ? hb : xb) + aoff;
      const f16* B0 = wpA + mat * 16384 + boff;
      const f16* B1 = wpB + mat * 16384 + boff;
      f16x8 a[2][4], b0[2][4], b1[2][4];
#pragma unroll
      for (int i = 0; i < 4; ++i) {
        a[0][i]  = *(const f16x8*)(A + i * 512);
        b0[0][i] = *(const f16x8*)(B0 + i * 512);
        b1[0][i] = *(const f16x8*)(B1 + i * 512);
      }
#pragma unroll
      for (int blk = 0; blk < 8; ++blk) {
        const int cur = blk & 1, nxt = cur ^ 1;
        if (blk < 7) {
#pragma unroll
          for (int i = 0; i < 4; ++i) {
            const int kk = (blk + 1) * 4 + i;
            a[nxt][i]  = *(const f16x8*)(A + kk * 512);
            b0[nxt][i] = *(const f16x8*)(B0 + kk * 512);
            b1[nxt][i] = *(const f16x8*)(B1 + kk * 512);
          }
        }
#pragma unroll
        for (int i = 0; i < 4; ++i) {
          f16x4 al  = __builtin_shufflevector(a[cur][i], a[cur][i], 0, 1, 2, 3);
          f16x4 ah  = __builtin_shufflevector(a[cur][i], a[cur][i], 4, 5, 6, 7);
          f16x4 b0l = __builtin_shufflevector(b0[cur][i], b0[cur][i], 0, 1, 2, 3);
          f16x4 b0h = __builtin_shufflevector(b0[cur][i], b0[cur][i], 4, 5, 6, 7);
          f16x4 b1l = __builtin_shufflevector(b1[cur][i], b1[cur][i], 0, 1, 2, 3);
          f16x4 b1h = __builtin_shufflevector(b1[cur][i], b1[cur][i], 4, 5, 6, 7);
          acc0 = MFMA16(al, b0l, acc0);
          acc1 = MFMA16(al, b1l, acc1);
          acc0 = MFMA16(ah, b0h, acc0);
          acc1 = MFMA16(ah, b1h, acc1);
        }
      }
    }

    // ---- spill z tile to LDS (C layout: col=lane&15, row=4*(lane>>4)+r) ----
    {
      const int r0 = wm * 16 + ((lane >> 4) & 3) * 4;
      const int cc = lane & 15;
#pragma unroll
      for (int r = 0; r < 4; ++r) {
        zl[r0 + r][g0 * 16 + cc]       = acc0[r];
        zl[r0 + r][(g0 + 1) * 16 + cc] = acc1[r];
      }
    }
    __syncthreads();

    // ---- gates + state update (i,f,g,o order) ----
#pragma unroll
    for (int e2 = 0; e2 < 2; ++e2) {
      const int e = tid + e2 * 512;
      const int row = e >> 4, hl = e & 15;
      const int hu = s * 16 + hl;
      const float zi = zl[row][hl]      + bias[j * 4096 + hu];
      const float zf = zl[row][16 + hl] + bias[j * 4096 + 1024 + hu];
      const float zg = zl[row][32 + hl] + bias[j * 4096 + 2048 + hu];
      const float zo = zl[row][48 + hl] + bias[j * 4096 + 3072 + hu];
      const float cp = g_c32[j][row][hu];
      const float cn = sigf(zf) * cp + sigf(zi) * tanh_(zg);
      const float hn = sigf(zo) * tanh_(cn);
      g_c32[j][row][hu] = cn;
      const int fi = ((((row >> 4) * 32 + (hu >> 5)) * 64 +
                       ((((hu >> 2) & 3) << 4) | (row & 15))) << 3) +
                     ((((hu >> 4) & 1) << 2) | (hu & 3));
      if (j < 3) g_c16[j][t & 1][fi] = (f16)cn;  // cell state feeds next layer (reference quirk)
      g_h16[j][t & 1][fi] = (f16)hn;
      if (j == 3 && t == TT - 1) out[(row << 10) + hu] = cn; // output = final cell state of layer 3
    }

    // ---- release + completion flag ----
    __builtin_amdgcn_fence(__ATOMIC_RELEASE, "agent");
    __syncthreads();
    if (tid == 0)
      __hip_atomic_fetch_add(&g_done[j][t], 1u, __ATOMIC_RELAXED, __HIP_MEMORY_SCOPE_AGENT);
  }
}

extern "C" void kernel_launch(void* const* d_in, const int* in_sizes, int n_in,
                              void* d_out, int out_size, void* d_ws, size_t ws_size,
                              hipStream_t stream) {
  const float* inp  = (const float*)d_in[0];
  const float* W    = (const float*)d_in[1];
  const float* U    = (const float*)d_in[2];
  const float* bias = (const float*)d_in[3];
  float* out = (float*)d_out;
  k_init<<<512, 256, 0, stream>>>();
  k_pack_in<<<4096, 512, 0, stream>>>(inp);
  k_pack_w<<<8192, 512, 0, stream>>>(W, U);
  k_main<<<256, 512, 0, stream>>>(bias, out);
}

// Round 4
// 7584.996 us; speedup vs baseline: 1.5654x; 1.5654x over previous
//
#include <hip/hip_runtime.h>

#define TT 128
#define BB 64
#define HH 1024
#define LL 4

typedef _Float16 f16;
typedef __attribute__((ext_vector_type(2))) _Float16 f16x2;
typedef __attribute__((ext_vector_type(4))) _Float16 f16x4;
typedef __attribute__((ext_vector_type(8))) _Float16 f16x8;
typedef __attribute__((ext_vector_type(4))) float f32x4;

// ---------------- persistent device buffers ----------------
// Fragment layout for a [64 rows x 1024 k] fp16 tensor (HW-verified in round 1):
//   flat = ((rg*32 + ktp)*64 + lane)*8 + e
//   rg = row>>4, ktp = k>>5, lane = ((k>>2)&3)<<4 | (row&15), e = ((k>>4)&1)<<2 | (k&3)
// A-frag for v_mfma_f32_16x16x16f16: m = lane&15, k = 4*(lane>>4)+e
__device__ __align__(16) f16 g_in16[TT][65536];           // inputs, frag layout per t
// write-once state slots: slot t+1 holds post-step-t state.
__device__ __align__(16) f16 g_c16[LL][TT + 1][65536];    // cell state fp16 (feeds next layer)
__device__ __align__(16) f16 g_h16[LL][TT + 1][65536];    // hidden state fp16 (U-matmul input)
__device__ __align__(16) float g_c32[LL][BB][HH];         // cell state master f32 (WG-private)
__device__ unsigned g_done[LL][TT];                       // completion counters (64 WGs each)

// ---------------- init: zero state slot 0 + flags + c32 ----------------
__global__ void k_init() {
  unsigned tid = blockIdx.x * blockDim.x + threadIdx.x;
  unsigned n = gridDim.x * blockDim.x;
  float* c32 = &g_c32[0][0][0];
  for (unsigned i = tid; i < LL * BB * HH; i += n) c32[i] = 0.f;
  for (unsigned i = tid; i < LL * 65536 / 2; i += n) {
    int jj = i >> 15, q = i & 32767;
    ((unsigned*)&g_h16[jj][0][0])[q] = 0u;
  }
  unsigned* pd = &g_done[0][0];
  for (unsigned i = tid; i < LL * TT; i += n) pd[i] = 0u;
}

// ---------------- pack inputs f32 -> fp16 fragment layout (unchanged, verified) ----------------
__global__ void k_pack_in(const float* __restrict__ inp) {
  int tid = blockIdx.x * blockDim.x + threadIdx.x;
  int t = tid >> 14, q = tid & 16383;
  int row = q >> 8, hu = (q & 255) << 2;
  const float4 x = *(const float4*)(inp + ((size_t)t << 16) + (row << 10) + hu);
  int rg = row >> 4, ktp = hu >> 5;
  int ln = (((hu >> 2) & 3) << 4) | (row & 15);
  int e0 = ((hu >> 4) & 1) << 2;
  f16x4 v = {(f16)x.x, (f16)x.y, (f16)x.z, (f16)x.w};
  *(f16x4*)&g_in16[t][(((rg * 32 + ktp) * 64 + ln) << 3) + e0] = v;
}

// ---------------- main persistent kernel ----------------
__device__ __forceinline__ float sigf(float x) { return 1.f / (1.f + __expf(-x)); }
__device__ __forceinline__ float tanh_(float x) {
  float q = __expf(-2.f * fabsf(x));
  return copysignf((1.f - q) / (1.f + q), x);
}
__device__ __forceinline__ f16x4 lo8(f16x8 v) { return __builtin_shufflevector(v, v, 0, 1, 2, 3); }
__device__ __forceinline__ f16x4 hi8(f16x8 v) { return __builtin_shufflevector(v, v, 4, 5, 6, 7); }
__device__ __forceinline__ void waitflag(const unsigned* p) {
  while (__hip_atomic_load(p, __ATOMIC_RELAXED, __HIP_MEMORY_SCOPE_AGENT) < 64u)
    __builtin_amdgcn_s_sleep(2);
}

#define MFMA16(A_, B_, C_) __builtin_amdgcn_mfma_f32_16x16x16f16(A_, B_, C_, 0, 0, 0)

// Decomposition: WG (j,s) owns 64 rows x 64 gate-cols (16 hidden units x 4 gates).
// Wave w: mat = w>>2 (0: x@W, 1: h@U), K-quarter kq = w&3 -> holds B-frags for its
// 64 cols x 256 K in 64 VGPRs, computes full 64x64 partial z; 8 partials reduced via LDS.
// Sync: round-1-proven WG-level protocol (tid0 waits + agent acquire fence + barrier;
// release fence + vmcnt drain + barrier + flag bump). Weights in VGPRs are immune to
// the acquire's L2 invalidate, so the r1 perf pathology (67MB/step re-stream) is gone.
__global__ __launch_bounds__(512, 2) void k_main(const float* __restrict__ W,
                                                 const float* __restrict__ U,
                                                 const float* __restrict__ bias,
                                                 float* __restrict__ out) {
  const int j = blockIdx.x >> 6, s = blockIdx.x & 63;
  const int tid = threadIdx.x, lane = tid & 63, wv = tid >> 6;
  const int mat = wv >> 2, kq = wv & 3;
  __shared__ float zl[16384];  // [w][row][32-colhalf], xor-swizzled, exactly 64 KiB

  // ---- one-time weight gather f32 -> fp16 regs (direct, no pack kernel) ----
  const float* src = (mat ? U : W) + (size_t)j * (HH * 4 * HH);
  const int colb = s * 16 + (lane & 15);
  const int kb0 = kq * 256 + ((lane >> 4) << 2);
  f16x8 Wr[32];
#pragma unroll
  for (int kk = 0; kk < 16; ++kk)
#pragma unroll
    for (int cfp = 0; cfp < 2; ++cfp) {
      f16x8 v;
#pragma unroll
      for (int hf = 0; hf < 2; ++hf)
#pragma unroll
        for (int e = 0; e < 4; ++e)
          v[hf * 4 + e] = (f16)src[(size_t)(kb0 + kk * 16 + e) * 4096 + (cfp * 2 + hf) * 1024 + colb];
      Wr[kk * 2 + cfp] = v;
    }

  // ---- per-thread epilogue constants ----
  const int row = tid >> 3, hl0 = (tid & 7) * 2;
  const int hu0 = s * 16 + hl0;
  float br[2][4];
#pragma unroll
  for (int el = 0; el < 2; ++el)
#pragma unroll
    for (int g = 0; g < 4; ++g) br[el][g] = bias[j * 4096 + g * 1024 + hu0 + el];
  const int fibase = ((((row >> 4) * 32 + (hu0 >> 5)) * 64 +
                       ((((hu0 >> 2) & 3) << 4) | (row & 15))) << 3) +
                     ((((hu0 >> 4) & 1) << 2) | (hu0 & 3));
  const int fib2 = fibase >> 1;  // u32 index (fibase provably even: hu0 is even)
  unsigned* const hPub = (unsigned*)&g_h16[j][0][0];  // 16-aligned base, u32-typed
  unsigned* const cPub = (unsigned*)&g_c16[j][0][0];
  float* c32p = &g_c32[j][row][hu0];
  const int ktp0 = kq * 8;

  for (int t = 0; t < TT; ++t) {
    // ---- WG-level dependency wait + acquire (round-1-proven protocol) ----
    if (tid == 0) {
      if (j > 0) waitflag(&g_done[j - 1][t]);   // cell state from layer below, step t
      if (t > 0) waitflag(&g_done[j][t - 1]);   // own layer's h from step t-1
      __builtin_amdgcn_fence(__ATOMIC_ACQUIRE, "agent");
    }
    __syncthreads();

    const f16* Ab = mat ? &g_h16[j][t][0]
                        : (j ? &g_c16[j - 1][t + 1][0] : &g_in16[t][0]);
    f16x8 a[2][4];
#pragma unroll
    for (int rf = 0; rf < 4; ++rf)
      a[0][rf] = *(const f16x8*)(Ab + (rf * 32 + ktp0) * 512 + lane * 8);

    f32x4 acc[4][4];
#pragma unroll
    for (int rf = 0; rf < 4; ++rf)
#pragma unroll
      for (int cf = 0; cf < 4; ++cf) acc[rf][cf] = (f32x4){0.f, 0.f, 0.f, 0.f};

#pragma unroll
    for (int kc = 0; kc < 8; ++kc) {
      if (kc < 7) {
#pragma unroll
        for (int rf = 0; rf < 4; ++rf)
          a[(kc + 1) & 1][rf] = *(const f16x8*)(Ab + (rf * 32 + ktp0 + kc + 1) * 512 + lane * 8);
      }
#pragma unroll
      for (int hf = 0; hf < 2; ++hf) {
        f16x4 a4[4];
#pragma unroll
        for (int rf = 0; rf < 4; ++rf)
          a4[rf] = hf ? hi8(a[kc & 1][rf]) : lo8(a[kc & 1][rf]);
#pragma unroll
        for (int cf = 0; cf < 4; ++cf) {
          const f16x8 wreg = Wr[(kc * 2 + hf) * 2 + (cf >> 1)];
          const f16x4 b4 = (cf & 1) ? hi8(wreg) : lo8(wreg);
#pragma unroll
          for (int rf = 0; rf < 4; ++rf) acc[rf][cf] = MFMA16(a4[rf], b4, acc[rf][cf]);
        }
      }
    }

    // ---- 8-wave reduction via 64 KiB LDS, two column-phases ----
    float gsum[2][4];
#pragma unroll
    for (int P = 0; P < 2; ++P) {
      __syncthreads();  // also protects zl reuse vs previous phase/step
#pragma unroll
      for (int rf = 0; rf < 4; ++rf)
#pragma unroll
        for (int ch = 0; ch < 2; ++ch) {
          const int cf = P * 2 + ch;
#pragma unroll
          for (int ri = 0; ri < 4; ++ri) {
            const int rr = rf * 16 + ((lane >> 4) << 2) + ri;
            const int c2 = ch * 16 + (lane & 15);
            zl[wv * 2048 + rr * 32 + (c2 ^ ((rr & 4) << 2))] = acc[rf][cf][ri];
          }
        }
      __syncthreads();
#pragma unroll
      for (int ch = 0; ch < 2; ++ch) {
        const int idx = row * 32 + ((ch * 16 + hl0) ^ ((row & 4) << 2));
        float sx = 0.f, sy = 0.f;
#pragma unroll
        for (int w = 0; w < 8; ++w) {
          const float2 v = *(const float2*)&zl[w * 2048 + idx];
          sx += v.x; sy += v.y;
        }
        gsum[0][P * 2 + ch] = sx;
        gsum[1][P * 2 + ch] = sy;
      }
    }

    // ---- gates + state update (i,f,g,o) ----
    float cns[2], hns[2];
#pragma unroll
    for (int el = 0; el < 2; ++el) {
      const float zi = gsum[el][0] + br[el][0];
      const float zf = gsum[el][1] + br[el][1];
      const float zg = gsum[el][2] + br[el][2];
      const float zo = gsum[el][3] + br[el][3];
      const float cp = c32p[el];
      const float cn = sigf(zf) * cp + sigf(zi) * tanh_(zg);
      c32p[el] = cn;
      cns[el] = cn;
      hns[el] = sigf(zo) * tanh_(cn);
    }
    {
      union { f16 h[2]; unsigned u; } ph, pc;
      ph.h[0] = (f16)hns[0]; ph.h[1] = (f16)hns[1];
      __hip_atomic_store(hPub + (size_t)(t + 1) * 32768 + fib2, ph.u,
                         __ATOMIC_RELAXED, __HIP_MEMORY_SCOPE_AGENT);
      if (j < 3) {
        pc.h[0] = (f16)cns[0]; pc.h[1] = (f16)cns[1];
        __hip_atomic_store(cPub + (size_t)(t + 1) * 32768 + fib2, pc.u,
                           __ATOMIC_RELAXED, __HIP_MEMORY_SCOPE_AGENT);
      }
      if (j == 3 && t == TT - 1) {
        out[(row << 10) + hu0] = cns[0];
        out[(row << 10) + hu0 + 1] = cns[1];
      }
    }
    // ---- release + completion flag (round-1-proven) ----
    __builtin_amdgcn_fence(__ATOMIC_RELEASE, "agent");
    asm volatile("s_waitcnt vmcnt(0)" ::: "memory");
    __syncthreads();
    if (tid == 0)
      __hip_atomic_fetch_add(&g_done[j][t], 1u, __ATOMIC_RELAXED, __HIP_MEMORY_SCOPE_AGENT);
  }
}

extern "C" void kernel_launch(void* const* d_in, const int* in_sizes, int n_in,
                              void* d_out, int out_size, void* d_ws, size_t ws_size,
                              hipStream_t stream) {
  const float* inp  = (const float*)d_in[0];
  const float* W    = (const float*)d_in[1];
  const float* U    = (const float*)d_in[2];
  const float* bias = (const float*)d_in[3];
  float* out = (float*)d_out;
  k_init<<<256, 256, 0, stream>>>();
  k_pack_in<<<4096, 512, 0, stream>>>(inp);
  k_main<<<256, 512, 0, stream>>>(W, U, bias, out);
}